// Round 1
// baseline (366.572 us; speedup 1.0000x reference)
//
#include <hip/hip_runtime.h>

typedef __bf16 bf16_t;
typedef bf16_t bf16x8 __attribute__((ext_vector_type(8)));
typedef float f32x4 __attribute__((ext_vector_type(4)));

#define S_LEN 2048
#define D_DIM 64
#define NUM_BH 64
#define QBLK 64
#define KVBLK 64

__device__ __forceinline__ unsigned short bf_bits(float x) {
  return __builtin_bit_cast(unsigned short, (bf16_t)x);
}

__device__ __forceinline__ bf16x8 load_cvt8(const float* __restrict__ src) {
  float4 f0 = *(const float4*)(src);
  float4 f1 = *(const float4*)(src + 4);
  bf16x8 r;
  r[0] = (bf16_t)f0.x; r[1] = (bf16_t)f0.y; r[2] = (bf16_t)f0.z; r[3] = (bf16_t)f0.w;
  r[4] = (bf16_t)f1.x; r[5] = (bf16_t)f1.y; r[6] = (bf16_t)f1.z; r[7] = (bf16_t)f1.w;
  return r;
}

__device__ __forceinline__ bf16x8 load_cvt8_scaled(const float* __restrict__ src, float s) {
  float4 f0 = *(const float4*)(src);
  float4 f1 = *(const float4*)(src + 4);
  bf16x8 r;
  r[0] = (bf16_t)(f0.x * s); r[1] = (bf16_t)(f0.y * s);
  r[2] = (bf16_t)(f0.z * s); r[3] = (bf16_t)(f0.w * s);
  r[4] = (bf16_t)(f1.x * s); r[5] = (bf16_t)(f1.y * s);
  r[6] = (bf16_t)(f1.z * s); r[7] = (bf16_t)(f1.w * s);
  return r;
}

__global__ __launch_bounds__(256) void attn_fwd_causal(
    const float* __restrict__ Q, const float* __restrict__ K,
    const float* __restrict__ V, float* __restrict__ O) {
  // LDS: K tile row-major [kv][d] swizzled; V tile transposed [d][kv] swizzled;
  // per-wave P buffer [16 q-rows][64 kv] swizzled.
  __shared__ __align__(16) unsigned short k_lds[KVBLK * D_DIM];
  __shared__ __align__(16) unsigned short vt_lds[D_DIM * KVBLK];
  __shared__ __align__(16) unsigned short p_lds[4][16 * KVBLK];

  const int tid = threadIdx.x;
  const int lane = tid & 63;
  const int w = tid >> 6;      // wave 0..3
  const int l15 = lane & 15;
  const int lg = lane >> 4;    // 0..3

  // Longest blocks (largest qtile) first.
  const int qtile = (int)gridDim.x - 1 - (int)blockIdx.x;
  const int bh = blockIdx.y;
  const int qbase = qtile * QBLK;

  const float* Qb = Q + (size_t)bh * S_LEN * D_DIM;
  const float* Kb = K + (size_t)bh * S_LEN * D_DIM;
  const float* Vb = V + (size_t)bh * S_LEN * D_DIM;
  float* Ob = O + (size_t)bh * S_LEN * D_DIM;

  // Q fragments hoisted to registers, scale 1/sqrt(64)=0.125 folded in.
  // A layout (16x16x32): row = lane&15, k-chunk = (lane>>4)*8 .. +7.
  bf16x8 qf[2];
  {
    const int qrow = qbase + w * 16 + l15;
    const float* qsrc = Qb + (size_t)qrow * D_DIM + lg * 8;
    qf[0] = load_cvt8_scaled(qsrc, 0.125f);
    qf[1] = load_cvt8_scaled(qsrc + 32, 0.125f);
  }

  f32x4 o_acc[4] = {{0.f,0.f,0.f,0.f},{0.f,0.f,0.f,0.f},
                    {0.f,0.f,0.f,0.f},{0.f,0.f,0.f,0.f}};
  float m_r[4] = {-INFINITY, -INFINITY, -INFINITY, -INFINITY};
  float l_r[4] = {0.f, 0.f, 0.f, 0.f};

  unsigned short* pw = p_lds[w];
  const int n_t = qtile + 1;

  for (int t = 0; t < n_t; ++t) {
    const int kvb = t * KVBLK;
    const bool diag = (t == n_t - 1);

    // ---- stage K tile: row-major [kv][d], byte ^= (row&7)<<4 ----
    #pragma unroll
    for (int i = 0; i < 2; ++i) {
      const int chunk = tid + i * 256;     // 0..511
      const int row = chunk >> 3;          // 0..63
      const int c8 = chunk & 7;            // 8-elem column chunk
      bf16x8 v8 = load_cvt8(Kb + (size_t)(kvb + row) * D_DIM + c8 * 8);
      const int off = (row * 128 + c8 * 16) ^ ((row & 7) << 4);
      *(bf16x8*)((char*)k_lds + off) = v8;
    }
    // ---- stage V tile transposed: [d][kv], packed kv-pairs ----
    {
      const int kv0 = (tid & 31) * 2;      // 0,2,..,62
      const int d0 = (tid >> 5) * 8;       // 0,8,..,56
      const float* s0 = Vb + (size_t)(kvb + kv0) * D_DIM + d0;
      const float* s1 = s0 + D_DIM;
      float4 a0 = *(const float4*)s0;
      float4 a1 = *(const float4*)(s0 + 4);
      float4 b0 = *(const float4*)s1;
      float4 b1 = *(const float4*)(s1 + 4);
      const float av[8] = {a0.x,a0.y,a0.z,a0.w,a1.x,a1.y,a1.z,a1.w};
      const float bv[8] = {b0.x,b0.y,b0.z,b0.w,b1.x,b1.y,b1.z,b1.w};
      #pragma unroll
      for (int e = 0; e < 8; ++e) {
        const int d = d0 + e;
        const unsigned int word =
            (unsigned int)bf_bits(av[e]) | ((unsigned int)bf_bits(bv[e]) << 16);
        const int off = (d * 128 + kv0 * 2) ^ ((d & 7) << 4);
        *(unsigned int*)((char*)vt_lds + off) = word;
      }
    }
    __syncthreads();

    // ---- QK^T: S[q 16][kv 64], per-wave. D layout: col=lane&15, row=4*lg+r ----
    float sj[4][4];  // [kv-subtile j][row r]
    #pragma unroll
    for (int j = 0; j < 4; ++j) {
      const bool live = (!diag) || (j <= w);
      if (live) {
        f32x4 acc = {0.f, 0.f, 0.f, 0.f};
        #pragma unroll
        for (int kd = 0; kd < 2; ++kd) {
          const int row = j * 16 + l15;  // K row (kv index) = B col
          const int off =
              (row * 128 + (kd * 32 + lg * 8) * 2) ^ ((row & 7) << 4);
          bf16x8 bf = *(const bf16x8*)((const char*)k_lds + off);
          acc = __builtin_amdgcn_mfma_f32_16x16x32_bf16(qf[kd], bf, acc, 0, 0, 0);
        }
        #pragma unroll
        for (int r = 0; r < 4; ++r) sj[j][r] = acc[r];
      } else {
        #pragma unroll
        for (int r = 0; r < 4; ++r) sj[j][r] = -INFINITY;
      }
    }
    if (diag) {
      // diagonal subtile j == w: mask kv_local > q_local
      #pragma unroll
      for (int r = 0; r < 4; ++r)
        if (l15 > 4 * lg + r) sj[w][r] = -INFINITY;
    }

    // ---- online softmax (rows 4*lg..4*lg+3, reduce across 16 lanes) ----
    float pmax[4];
    #pragma unroll
    for (int r = 0; r < 4; ++r)
      pmax[r] = fmaxf(fmaxf(sj[0][r], sj[1][r]), fmaxf(sj[2][r], sj[3][r]));
    #pragma unroll
    for (int x = 1; x < 16; x <<= 1) {
      #pragma unroll
      for (int r = 0; r < 4; ++r)
        pmax[r] = fmaxf(pmax[r], __shfl_xor(pmax[r], x, 64));
    }
    float sf[4];
    #pragma unroll
    for (int r = 0; r < 4; ++r) {
      const float mnew = fmaxf(m_r[r], pmax[r]);
      sf[r] = expf(m_r[r] - mnew);   // first tile: exp(-inf)=0
      m_r[r] = mnew;
    }
    float p[4][4];
    #pragma unroll
    for (int j = 0; j < 4; ++j) {
      #pragma unroll
      for (int r = 0; r < 4; ++r)
        p[j][r] = expf(sj[j][r] - m_r[r]);   // masked: exp(-inf)=0
    }
    float psum[4];
    #pragma unroll
    for (int r = 0; r < 4; ++r)
      psum[r] = (p[0][r] + p[1][r]) + (p[2][r] + p[3][r]);
    #pragma unroll
    for (int x = 1; x < 16; x <<= 1) {
      #pragma unroll
      for (int r = 0; r < 4; ++r)
        psum[r] += __shfl_xor(psum[r], x, 64);
    }
    #pragma unroll
    for (int r = 0; r < 4; ++r)
      l_r[r] = l_r[r] * sf[r] + psum[r];
    #pragma unroll
    for (int j = 0; j < 4; ++j) {
      #pragma unroll
      for (int r = 0; r < 4; ++r)
        o_acc[j][r] *= sf[r];
    }

    // ---- P -> per-wave LDS (layout conversion D-layout -> A-fragment) ----
    #pragma unroll
    for (int j = 0; j < 4; ++j) {
      #pragma unroll
      for (int r = 0; r < 4; ++r) {
        const int prow = 4 * lg + r;
        const int off =
            (prow * 128 + (j * 16 + l15) * 2) ^ ((prow & 7) << 4);
        *(unsigned short*)((char*)pw + off) = bf_bits(p[j][r]);
      }
    }
    asm volatile("s_waitcnt lgkmcnt(0)" ::: "memory");  // same-wave RAW fence

    // ---- PV: O[q 16][d 64] += P[16][64] * V[64][64] ----
    const int kcmax = (diag && w < 2) ? 0 : 1;  // skip fully-masked kv chunk
    #pragma unroll
    for (int kc = 0; kc < 2; ++kc) {
      if (kc > kcmax) break;
      const int aoff =
          (l15 * 128 + (kc * 32 + lg * 8) * 2) ^ ((l15 & 7) << 4);
      bf16x8 af = *(const bf16x8*)((const char*)pw + aoff);
      #pragma unroll
      for (int j = 0; j < 4; ++j) {
        const int vrow = j * 16 + l15;  // d index = B col
        const int voff =
            (vrow * 128 + (kc * 32 + lg * 8) * 2) ^ ((vrow & 7) << 4);
        bf16x8 vf = *(const bf16x8*)((const char*)vt_lds + voff);
        o_acc[j] = __builtin_amdgcn_mfma_f32_16x16x32_bf16(af, vf, o_acc[j], 0, 0, 0);
      }
    }
    __syncthreads();  // protect LDS before next-tile restage
  }

  // ---- epilogue: normalize by l and store fp32 ----
  float inv_l[4];
  #pragma unroll
  for (int r = 0; r < 4; ++r) inv_l[r] = 1.0f / l_r[r];
  const int qrow0 = qbase + w * 16 + 4 * lg;
  #pragma unroll
  for (int j = 0; j < 4; ++j) {
    #pragma unroll
    for (int r = 0; r < 4; ++r)
      Ob[(size_t)(qrow0 + r) * D_DIM + j * 16 + l15] = o_acc[j][r] * inv_l[r];
  }
}

extern "C" void kernel_launch(void* const* d_in, const int* in_sizes, int n_in,
                              void* d_out, int out_size, void* d_ws, size_t ws_size,
                              hipStream_t stream) {
  (void)in_sizes; (void)n_in; (void)out_size; (void)d_ws; (void)ws_size;
  const float* q = (const float*)d_in[0];
  const float* k = (const float*)d_in[1];
  const float* v = (const float*)d_in[2];
  // d_in[3] is the causal mask; it is exactly triu(ones,k=1) so we recompute
  // causality from indices instead of reading it.
  float* o = (float*)d_out;
  dim3 grid(S_LEN / QBLK, NUM_BH, 1);
  attn_fwd_causal<<<grid, dim3(256, 1, 1), 0, stream>>>(q, k, v, o);
}

// Round 3
// 282.673 us; speedup vs baseline: 1.2968x; 1.2968x over previous
//
#include <hip/hip_runtime.h>

typedef __bf16 bf16_t;
typedef bf16_t bf16x8 __attribute__((ext_vector_type(8)));
typedef float f32x4 __attribute__((ext_vector_type(4)));

#define S_LEN 2048
#define D_DIM 64
#define NUM_BH 64
#define QBLK 128     // 8 waves x 16 q-rows
#define KVBLK 64
#define NEG_BIG (-1e30f)                    // finite sentinel (fast-math safe)
#define QSCALE 0.18033688011112042f         // 0.125 * log2(e): base-2 softmax

__device__ __forceinline__ unsigned short bf_bits(float x) {
  return __builtin_bit_cast(unsigned short, (bf16_t)x);
}

__device__ __forceinline__ bf16x8 load_cvt8_scaled(const float* __restrict__ src, float s) {
  f32x4 f0 = *(const f32x4*)(src);
  f32x4 f1 = *(const f32x4*)(src + 4);
  bf16x8 r;
  r[0] = (bf16_t)(f0[0] * s); r[1] = (bf16_t)(f0[1] * s);
  r[2] = (bf16_t)(f0[2] * s); r[3] = (bf16_t)(f0[3] * s);
  r[4] = (bf16_t)(f1[0] * s); r[5] = (bf16_t)(f1[1] * s);
  r[6] = (bf16_t)(f1[2] * s); r[7] = (bf16_t)(f1[3] * s);
  return r;
}

__global__ __launch_bounds__(512) void attn_fwd3(
    const float* __restrict__ Q, const float* __restrict__ K,
    const float* __restrict__ V, float* __restrict__ O) {
  // Double-buffered K (row-major [kv][d]) and V^T ([d][kv]), XOR-swizzled rows.
  __shared__ __align__(16) unsigned short k_lds[2][KVBLK * D_DIM];
  __shared__ __align__(16) unsigned short v_lds[2][D_DIM * KVBLK];
  __shared__ __align__(16) unsigned short p_lds[8][16 * KVBLK];  // per-wave P

  const int tid = threadIdx.x;
  const int lane = tid & 63;
  const int w = tid >> 6;        // wave 0..7
  const int l15 = lane & 15;
  const int lg = lane >> 4;      // 0..3

  const int qtile = (int)gridDim.x - 1 - (int)blockIdx.x;  // longest first
  const int bh = blockIdx.y;
  const int qbase = qtile * QBLK;
  const int qw = qbase + w * 16;   // this wave's first q-row

  const float* Qb = Q + (size_t)bh * S_LEN * D_DIM;
  const float* Kb = K + (size_t)bh * S_LEN * D_DIM;
  const float* Vb = V + (size_t)bh * S_LEN * D_DIM;
  float* Ob = O + (size_t)bh * S_LEN * D_DIM;

  // Staging decomposition over 512 threads:
  // K: thread -> (row = tid>>3, 8-col chunk = tid&7): one bf16x8 ds_write_b128.
  // V^T: thread -> (kv-pair kp = tid&31, d-group dg = tid>>5 covering 4 d):
  //      4 packed u32 ds_write_b32.
  const int krow = tid >> 3, kc8 = tid & 7;
  const int vkp = tid & 31, vdg = tid >> 5;

  // Q fragment (A layout: row = lane&15, k-chunk = (lane>>4)*8), scale folded.
  bf16x8 qf[2];
  {
    const float* qsrc = Qb + (size_t)(qw + l15) * D_DIM + lg * 8;
    qf[0] = load_cvt8_scaled(qsrc, QSCALE);
    qf[1] = load_cvt8_scaled(qsrc + 32, QSCALE);
  }

  f32x4 o_acc[4] = {{0.f,0.f,0.f,0.f},{0.f,0.f,0.f,0.f},
                    {0.f,0.f,0.f,0.f},{0.f,0.f,0.f,0.f}};
  float m_r[4] = {NEG_BIG, NEG_BIG, NEG_BIG, NEG_BIG};
  float l_r[4] = {0.f, 0.f, 0.f, 0.f};

  unsigned short* pw = p_lds[w];
  const int n_t = 2 * qtile + 2;   // kv tiles: [0, qbase+128)

  f32x4 pk0, pk1, pv0, pv1;        // prefetch registers

  auto stage_load = [&](int kvb) {
    const float* ks = Kb + (size_t)(kvb + krow) * D_DIM + kc8 * 8;
    pk0 = *(const f32x4*)ks;
    pk1 = *(const f32x4*)(ks + 4);
    const float* vs = Vb + (size_t)(kvb + vkp * 2) * D_DIM + vdg * 4;
    pv0 = *(const f32x4*)vs;
    pv1 = *(const f32x4*)(vs + D_DIM);
  };
  auto stage_store = [&](int buf) {
    bf16x8 k8;
    k8[0] = (bf16_t)pk0[0]; k8[1] = (bf16_t)pk0[1];
    k8[2] = (bf16_t)pk0[2]; k8[3] = (bf16_t)pk0[3];
    k8[4] = (bf16_t)pk1[0]; k8[5] = (bf16_t)pk1[1];
    k8[6] = (bf16_t)pk1[2]; k8[7] = (bf16_t)pk1[3];
    const int koff = (krow * 128 + kc8 * 16) ^ ((krow & 7) << 4);
    *(bf16x8*)((char*)k_lds[buf] + koff) = k8;
    #pragma unroll
    for (int e = 0; e < 4; ++e) {
      const int d = vdg * 4 + e;
      const unsigned int word = (unsigned int)bf_bits(pv0[e]) |
                                ((unsigned int)bf_bits(pv1[e]) << 16);
      const int voff = (d * 128 + vkp * 4) ^ ((d & 7) << 4);
      *(unsigned int*)((char*)v_lds[buf] + voff) = word;
    }
  };

  // prologue: stage tile 0 into buffer 0
  stage_load(0);
  stage_store(0);
  __syncthreads();

  for (int t = 0; t < n_t; ++t) {
    const int cur = t & 1;
    const int kvb = t * KVBLK;
    const bool last = (t == n_t - 1);

    if (!last) stage_load(kvb + KVBLK);   // issue next-tile global loads early

    if (kvb <= qw) {   // wave has at least one live kv in this tile
      const unsigned short* kl = k_lds[cur];
      const unsigned short* vl = v_lds[cur];

      // ---- QK^T: S^[q 16][kv 64]; D layout col=l15(kv), row=4*lg+r(q) ----
      float sj[4][4];
      #pragma unroll
      for (int j = 0; j < 4; ++j) {
        const int rel = kvb + 16 * j - qw;   // multiple of 16
        if (rel <= 0) {
          f32x4 acc = {0.f, 0.f, 0.f, 0.f};
          #pragma unroll
          for (int kd = 0; kd < 2; ++kd) {
            const int row = j * 16 + l15;
            const int off = (row * 128 + kd * 64 + lg * 16) ^ ((row & 7) << 4);
            bf16x8 bf = *(const bf16x8*)((const char*)kl + off);
            acc = __builtin_amdgcn_mfma_f32_16x16x32_bf16(qf[kd], bf, acc, 0, 0, 0);
          }
          #pragma unroll
          for (int r = 0; r < 4; ++r) sj[j][r] = acc[r];
          if (rel == 0) {   // diagonal subtile: mask kv_local > q_local
            #pragma unroll
            for (int r = 0; r < 4; ++r)
              if (l15 > 4 * lg + r) sj[j][r] = NEG_BIG;
          }
        } else {
          #pragma unroll
          for (int r = 0; r < 4; ++r) sj[j][r] = NEG_BIG;
        }
      }

      // ---- online softmax (base-2 domain, finite sentinels) ----
      float pmax[4];
      #pragma unroll
      for (int r = 0; r < 4; ++r)
        pmax[r] = fmaxf(fmaxf(sj[0][r], sj[1][r]), fmaxf(sj[2][r], sj[3][r]));
      #pragma unroll
      for (int x = 1; x < 16; x <<= 1) {
        #pragma unroll
        for (int r = 0; r < 4; ++r)
          pmax[r] = fmaxf(pmax[r], __shfl_xor(pmax[r], x, 64));
      }
      float sf[4];
      #pragma unroll
      for (int r = 0; r < 4; ++r) {
        const float mnew = fmaxf(m_r[r], pmax[r]);
        sf[r] = exp2f(m_r[r] - mnew);   // first live tile: exp2(-1e30) = 0
        m_r[r] = mnew;
      }
      float p[4][4];
      #pragma unroll
      for (int j = 0; j < 4; ++j) {
        #pragma unroll
        for (int r = 0; r < 4; ++r)
          p[j][r] = exp2f(sj[j][r] - m_r[r]);   // masked: exp2(~-1e30) = 0
      }
      float psum[4];
      #pragma unroll
      for (int r = 0; r < 4; ++r)
        psum[r] = (p[0][r] + p[1][r]) + (p[2][r] + p[3][r]);
      #pragma unroll
      for (int x = 1; x < 16; x <<= 1) {
        #pragma unroll
        for (int r = 0; r < 4; ++r)
          psum[r] += __shfl_xor(psum[r], x, 64);
      }
      #pragma unroll
      for (int r = 0; r < 4; ++r)
        l_r[r] = l_r[r] * sf[r] + psum[r];
      #pragma unroll
      for (int j = 0; j < 4; ++j) {
        #pragma unroll
        for (int r = 0; r < 4; ++r)
          o_acc[j][r] *= sf[r];
      }

      // ---- P -> per-wave LDS (D-layout -> A-fragment layout) ----
      #pragma unroll
      for (int j = 0; j < 4; ++j) {
        #pragma unroll
        for (int r = 0; r < 4; ++r) {
          const int prow = 4 * lg + r;
          const int off =
              (prow * 128 + (j * 16 + l15) * 2) ^ ((prow & 7) << 4);
          *(unsigned short*)((char*)pw + off) = bf_bits(p[j][r]);
        }
      }
      asm volatile("s_waitcnt lgkmcnt(0)" ::: "memory");  // same-wave RAW fence

      // ---- PV: O[q 16][d 64] += P[16][64] * V[64][64] ----
      const int kcmax = (kvb + 32 <= qw) ? 1 : 0;  // skip fully-masked chunk
      #pragma unroll
      for (int kc = 0; kc < 2; ++kc) {
        if (kc > kcmax) break;
        const int aoff = (l15 * 128 + kc * 64 + lg * 16) ^ ((l15 & 7) << 4);
        bf16x8 af = *(const bf16x8*)((const char*)pw + aoff);
        #pragma unroll
        for (int j = 0; j < 4; ++j) {
          const int vrow = j * 16 + l15;   // d index
          const int voff = (vrow * 128 + kc * 64 + lg * 16) ^ ((vrow & 7) << 4);
          bf16x8 vf = *(const bf16x8*)((const char*)vl + voff);
          o_acc[j] = __builtin_amdgcn_mfma_f32_16x16x32_bf16(af, vf, o_acc[j], 0, 0, 0);
        }
      }
    }

    if (!last) stage_store(cur ^ 1);   // convert + write next tile's LDS buffer
    __syncthreads();                   // one barrier per tile (dbuf)
  }

  // ---- epilogue: normalize by l and store fp32 ----
  float inv_l[4];
  #pragma unroll
  for (int r = 0; r < 4; ++r) inv_l[r] = 1.0f / l_r[r];
  const int qrow0 = qw + 4 * lg;
  #pragma unroll
  for (int j = 0; j < 4; ++j) {
    #pragma unroll
    for (int r = 0; r < 4; ++r)
      Ob[(size_t)(qrow0 + r) * D_DIM + j * 16 + l15] = o_acc[j][r] * inv_l[r];
  }
}

extern "C" void kernel_launch(void* const* d_in, const int* in_sizes, int n_in,
                              void* d_out, int out_size, void* d_ws, size_t ws_size,
                              hipStream_t stream) {
  (void)in_sizes; (void)n_in; (void)out_size; (void)d_ws; (void)ws_size;
  const float* q = (const float*)d_in[0];
  const float* k = (const float*)d_in[1];
  const float* v = (const float*)d_in[2];
  // d_in[3] (causal mask) is exactly triu(ones,k=1): recomputed from indices.
  float* o = (float*)d_out;
  attn_fwd3<<<dim3(S_LEN / QBLK, NUM_BH), dim3(512, 1, 1), 0, stream>>>(q, k, v, o);
}

// Round 4
// 166.476 us; speedup vs baseline: 2.2020x; 1.6980x over previous
//
#include <hip/hip_runtime.h>

typedef __bf16 bf16_t;
typedef bf16_t bf16x8 __attribute__((ext_vector_type(8)));
typedef float f32x4 __attribute__((ext_vector_type(4)));
typedef unsigned int u32x2 __attribute__((ext_vector_type(2)));

#define S_LEN 2048
#define D_DIM 64
#define NUM_BH 64
#define QBLK 128     // 8 waves x 16 q-rows
#define KVBLK 64
#define NEG_BIG (-1e30f)                    // finite sentinel (fast-math safe)
#define QSCALE 0.18033688011112042f         // 0.125 * log2(e): base-2 softmax

__device__ __forceinline__ unsigned short bf_bits(float x) {
  return __builtin_bit_cast(unsigned short, (bf16_t)x);
}
__device__ __forceinline__ unsigned int pack2(float a, float b) {
  return (unsigned int)bf_bits(a) | ((unsigned int)bf_bits(b) << 16);
}

__device__ __forceinline__ bf16x8 load_cvt8_scaled(const float* __restrict__ src, float s) {
  f32x4 f0 = *(const f32x4*)(src);
  f32x4 f1 = *(const f32x4*)(src + 4);
  bf16x8 r;
  r[0] = (bf16_t)(f0[0] * s); r[1] = (bf16_t)(f0[1] * s);
  r[2] = (bf16_t)(f0[2] * s); r[3] = (bf16_t)(f0[3] * s);
  r[4] = (bf16_t)(f1[0] * s); r[5] = (bf16_t)(f1[1] * s);
  r[6] = (bf16_t)(f1[2] * s); r[7] = (bf16_t)(f1[3] * s);
  return r;
}

__global__ __launch_bounds__(512) void attn_fwd4(
    const float* __restrict__ Q, const float* __restrict__ K,
    const float* __restrict__ V, float* __restrict__ O) {
  // Double-buffered K (row-major [kv][d]) and V^T ([d][kv]), XOR-swizzled rows.
  __shared__ __align__(16) unsigned short k_lds[2][KVBLK * D_DIM];
  __shared__ __align__(16) unsigned short v_lds[2][D_DIM * KVBLK];
  __shared__ __align__(16) unsigned short p_lds[8][16 * KVBLK];  // per-wave P

  const int tid = threadIdx.x;
  const int lane = tid & 63;
  const int w = tid >> 6;        // wave 0..7
  const int l15 = lane & 15;
  const int lg = lane >> 4;      // 0..3

  const int qtile = (int)gridDim.x - 1 - (int)blockIdx.x;  // longest first
  const int bh = blockIdx.y;
  const int qbase = qtile * QBLK;
  const int qw = qbase + w * 16;   // this wave's first q-row

  const float* Qb = Q + (size_t)bh * S_LEN * D_DIM;
  const float* Kb = K + (size_t)bh * S_LEN * D_DIM;
  const float* Vb = V + (size_t)bh * S_LEN * D_DIM;
  float* Ob = O + (size_t)bh * S_LEN * D_DIM;

  // Staging decomposition over 512 threads (same as verified r3).
  const int krow = tid >> 3, kc8 = tid & 7;
  const int vkp = tid & 31, vdg = tid >> 5;

  // Q fragment (per-lane: row l15, k-chunk lg*8), scale folded. Used as the
  // B operand of the swapped QK^T (B col = q = l15).
  bf16x8 qf[2];
  {
    const float* qsrc = Qb + (size_t)(qw + l15) * D_DIM + lg * 8;
    qf[0] = load_cvt8_scaled(qsrc, QSCALE);
    qf[1] = load_cvt8_scaled(qsrc + 32, QSCALE);
  }

  // O^T accumulator: col(l15)=q, row(4*lg+r)=d-local; subtile j: d=j*16+4lg+r.
  f32x4 o_acc[4] = {{0.f,0.f,0.f,0.f},{0.f,0.f,0.f,0.f},
                    {0.f,0.f,0.f,0.f},{0.f,0.f,0.f,0.f}};
  // Per-lane softmax state for q-row (qw + l15); lg groups hold replicas.
  float m_r = NEG_BIG;
  float l_r = 0.f;

  unsigned short* pw = p_lds[w];
  const int n_t = 2 * qtile + 2;   // kv tiles: [0, qbase+128)

  f32x4 pk0, pk1, pv0, pv1;        // prefetch registers

  auto stage_load = [&](int kvb) {
    const float* ks = Kb + (size_t)(kvb + krow) * D_DIM + kc8 * 8;
    pk0 = *(const f32x4*)ks;
    pk1 = *(const f32x4*)(ks + 4);
    const float* vs = Vb + (size_t)(kvb + vkp * 2) * D_DIM + vdg * 4;
    pv0 = *(const f32x4*)vs;
    pv1 = *(const f32x4*)(vs + D_DIM);
  };
  auto stage_store = [&](int buf) {
    bf16x8 k8;
    k8[0] = (bf16_t)pk0[0]; k8[1] = (bf16_t)pk0[1];
    k8[2] = (bf16_t)pk0[2]; k8[3] = (bf16_t)pk0[3];
    k8[4] = (bf16_t)pk1[0]; k8[5] = (bf16_t)pk1[1];
    k8[6] = (bf16_t)pk1[2]; k8[7] = (bf16_t)pk1[3];
    const int koff = (krow * 128 + kc8 * 16) ^ ((krow & 7) << 4);
    *(bf16x8*)((char*)k_lds[buf] + koff) = k8;
    #pragma unroll
    for (int e = 0; e < 4; ++e) {
      const int d = vdg * 4 + e;
      const unsigned int word = pack2(pv0[e], pv1[e]);
      const int voff = (d * 128 + vkp * 4) ^ ((d & 7) << 4);
      *(unsigned int*)((char*)v_lds[buf] + voff) = word;
    }
  };

  // prologue: stage tile 0 into buffer 0
  stage_load(0);
  stage_store(0);
  __syncthreads();

  for (int t = 0; t < n_t; ++t) {
    const int cur = t & 1;
    const int kvb = t * KVBLK;
    const bool last = (t == n_t - 1);

    if (!last) stage_load(kvb + KVBLK);   // issue next-tile global loads early

    if (kvb <= qw) {   // wave has at least one live kv in this tile
      const unsigned short* kl = k_lds[cur];
      const unsigned short* vl = v_lds[cur];

      // ---- swapped QK^T: S^T[kv][q]; lane holds 16 scores of q-row l15,
      //      kv = kvb + j*16 + 4*lg + r ----
      float sj[4][4];
      #pragma unroll
      for (int j = 0; j < 4; ++j) {
        const int rel = kvb + 16 * j - qw;   // multiple of 16
        if (rel <= 0) {
          f32x4 acc = {0.f, 0.f, 0.f, 0.f};
          #pragma unroll
          for (int kd = 0; kd < 2; ++kd) {
            const int row = j * 16 + l15;
            const int off = (row * 128 + kd * 64 + lg * 16) ^ ((row & 7) << 4);
            bf16x8 kf = *(const bf16x8*)((const char*)kl + off);
            // A = K-frag (rows = kv), B = Q-frag (cols = q)
            acc = __builtin_amdgcn_mfma_f32_16x16x32_bf16(kf, qf[kd], acc, 0, 0, 0);
          }
          #pragma unroll
          for (int r = 0; r < 4; ++r) sj[j][r] = acc[r];
          if (rel == 0) {   // diagonal subtile: mask kv_local > q_local
            #pragma unroll
            for (int r = 0; r < 4; ++r)
              if (4 * lg + r > l15) sj[j][r] = NEG_BIG;
          }
        } else {
          #pragma unroll
          for (int r = 0; r < 4; ++r) sj[j][r] = NEG_BIG;
        }
      }

      // ---- online softmax: in-lane tree + 2 shuffles (base-2 domain) ----
      float mx01 = fmaxf(fmaxf(sj[0][0], sj[0][1]), fmaxf(sj[0][2], sj[0][3]));
      float mx23 = fmaxf(fmaxf(sj[1][0], sj[1][1]), fmaxf(sj[1][2], sj[1][3]));
      float mx45 = fmaxf(fmaxf(sj[2][0], sj[2][1]), fmaxf(sj[2][2], sj[2][3]));
      float mx67 = fmaxf(fmaxf(sj[3][0], sj[3][1]), fmaxf(sj[3][2], sj[3][3]));
      float pmax = fmaxf(fmaxf(mx01, mx23), fmaxf(mx45, mx67));
      pmax = fmaxf(pmax, __shfl_xor(pmax, 16, 64));
      pmax = fmaxf(pmax, __shfl_xor(pmax, 32, 64));

      const float mnew = fmaxf(m_r, pmax);
      const float sf = exp2f(m_r - mnew);   // first live tile: exp2(-1e30)=0
      m_r = mnew;

      float p[4][4];
      #pragma unroll
      for (int j = 0; j < 4; ++j) {
        #pragma unroll
        for (int r = 0; r < 4; ++r)
          p[j][r] = exp2f(sj[j][r] - m_r);   // masked -> 0
      }
      float s01 = (p[0][0] + p[0][1]) + (p[0][2] + p[0][3]);
      float s23 = (p[1][0] + p[1][1]) + (p[1][2] + p[1][3]);
      float s45 = (p[2][0] + p[2][1]) + (p[2][2] + p[2][3]);
      float s67 = (p[3][0] + p[3][1]) + (p[3][2] + p[3][3]);
      float psum = (s01 + s23) + (s45 + s67);
      psum += __shfl_xor(psum, 16, 64);
      psum += __shfl_xor(psum, 32, 64);

      l_r = l_r * sf + psum;
      #pragma unroll
      for (int j = 0; j < 4; ++j)
        o_acc[j] *= sf;

      // ---- P -> per-wave LDS: one b64 per j (row q=l15, cols j*16+4lg..+3) ----
      #pragma unroll
      for (int j = 0; j < 4; ++j) {
        u32x2 wv;
        wv[0] = pack2(p[j][0], p[j][1]);
        wv[1] = pack2(p[j][2], p[j][3]);
        const int off = (l15 * 128 + (j * 16 + 4 * lg) * 2) ^ ((l15 & 7) << 4);
        *(u32x2*)((char*)pw + off) = wv;
      }
      asm volatile("s_waitcnt lgkmcnt(0)" ::: "memory");  // same-wave RAW fence

      // ---- swapped PV: O^T[d][q] += V^T-frag (A, rows=d) x P^T-frag (B, cols=q) ----
      const int kcmax = (kvb + 32 <= qw) ? 1 : 0;  // skip fully-masked chunk
      #pragma unroll
      for (int kc = 0; kc < 2; ++kc) {
        if (kc > kcmax) break;
        const int poff = (l15 * 128 + kc * 64 + lg * 16) ^ ((l15 & 7) << 4);
        bf16x8 pf = *(const bf16x8*)((const char*)pw + poff);
        #pragma unroll
        for (int j = 0; j < 4; ++j) {
          const int vrow = j * 16 + l15;   // d index
          const int voff = (vrow * 128 + kc * 64 + lg * 16) ^ ((vrow & 7) << 4);
          bf16x8 vf = *(const bf16x8*)((const char*)vl + voff);
          o_acc[j] = __builtin_amdgcn_mfma_f32_16x16x32_bf16(vf, pf, o_acc[j], 0, 0, 0);
        }
      }
    }

    if (!last) stage_store(cur ^ 1);   // convert + write next tile's LDS buffer
    __syncthreads();                   // one barrier per tile (dbuf)
  }

  // ---- epilogue: normalize, store 4x float4 per lane (O[q][d], d chunks) ----
  const float inv_l = 1.0f / l_r;
  float* orow = Ob + (size_t)(qw + l15) * D_DIM + 4 * lg;
  #pragma unroll
  for (int j = 0; j < 4; ++j) {
    float4 st;
    st.x = o_acc[j][0] * inv_l;
    st.y = o_acc[j][1] * inv_l;
    st.z = o_acc[j][2] * inv_l;
    st.w = o_acc[j][3] * inv_l;
    *(float4*)(orow + j * 16) = st;
  }
}

extern "C" void kernel_launch(void* const* d_in, const int* in_sizes, int n_in,
                              void* d_out, int out_size, void* d_ws, size_t ws_size,
                              hipStream_t stream) {
  (void)in_sizes; (void)n_in; (void)out_size; (void)d_ws; (void)ws_size;
  const float* q = (const float*)d_in[0];
  const float* k = (const float*)d_in[1];
  const float* v = (const float*)d_in[2];
  // d_in[3] (causal mask) is exactly triu(ones,k=1): recomputed from indices.
  float* o = (float*)d_out;
  attn_fwd4<<<dim3(S_LEN / QBLK, NUM_BH), dim3(512, 1, 1), 0, stream>>>(q, k, v, o);
}